// Round 2
// baseline (1845.661 us; speedup 1.0000x reference)
//
#include <hip/hip_runtime.h>
#include <math.h>

#define N_NODES 100000
#define N_EDGES 3200000
#define N_FEAT  512
#define N_HID   16
#define N_CLS   40

// ---------------- zero fill ----------------
__global__ void k_zero(float4* __restrict__ p, int n4) {
    int i = blockIdx.x * 256 + threadIdx.x;
    if (i < n4) p[i] = make_float4(0.f, 0.f, 0.f, 0.f);
}

// ---------------- GEMM1: support1[N,16] = X[N,512] @ W1[512,16] ----------------
// W1^T staged in LDS as [16][512]. Each quarter-wave (16 lanes) owns 4 rows.
// Lane (q,sub): rows rbase..rbase+3, feature slice f = i*64 + sub*4 (i=0..7).
// X loads: 16 lanes * float4 = 256B contiguous per row per iter (coalesced).
// W reads: ds_read_b128, 2-way bank alias (free) + cross-quarter broadcast.
__global__ __launch_bounds__(256) void k_gemm1(const float* __restrict__ x,
                                               const float* __restrict__ W1,
                                               float* __restrict__ out) {
    __shared__ float W1T[16 * 512];
    const int tid = threadIdx.x;
    #pragma unroll
    for (int k = 0; k < 32; ++k) {
        int idx = tid + k * 256;          // 0..8191 over W1[512][16]
        int f = idx >> 4, j = idx & 15;
        W1T[j * 512 + f] = W1[idx];
    }
    __syncthreads();

    const int wave = tid >> 6;
    const int lane = tid & 63;
    const int q    = lane >> 4;
    const int sub  = lane & 15;
    const int rbase = blockIdx.x * 64 + wave * 16 + q * 4;

    float acc[4][16];
    #pragma unroll
    for (int r = 0; r < 4; ++r)
        #pragma unroll
        for (int j = 0; j < 16; ++j) acc[r][j] = 0.f;

    #pragma unroll
    for (int i = 0; i < 8; ++i) {
        const int f = i * 64 + sub * 4;
        float4 v[4];
        #pragma unroll
        for (int r = 0; r < 4; ++r) {
            if (rbase + r < N_NODES)
                v[r] = *(const float4*)&x[(size_t)(rbase + r) * N_FEAT + f];
            else
                v[r] = make_float4(0.f, 0.f, 0.f, 0.f);
        }
        #pragma unroll
        for (int j = 0; j < 16; ++j) {
            const float4 w4 = *(const float4*)&W1T[j * 512 + f];
            #pragma unroll
            for (int r = 0; r < 4; ++r) {
                acc[r][j] += v[r].x * w4.x + v[r].y * w4.y
                           + v[r].z * w4.z + v[r].w * w4.w;
            }
        }
    }

    // butterfly sum over the 16 lanes of the quarter (xor bits 0..3)
    #pragma unroll
    for (int m = 1; m <= 8; m <<= 1) {
        #pragma unroll
        for (int r = 0; r < 4; ++r)
            #pragma unroll
            for (int j = 0; j < 16; ++j)
                acc[r][j] += __shfl_xor(acc[r][j], m, 64);
    }

    // lane `sub` writes column `sub` of each of its 4 rows.
    // select acc[r][sub] without dynamic register indexing (avoid scratch).
    float val[4];
    #pragma unroll
    for (int r = 0; r < 4; ++r) val[r] = acc[r][0];
    #pragma unroll
    for (int j = 1; j < 16; ++j) {
        #pragma unroll
        for (int r = 0; r < 4; ++r)
            val[r] = (sub == j) ? acc[r][j] : val[r];
    }
    #pragma unroll
    for (int r = 0; r < 4; ++r) {
        if (rbase + r < N_NODES)
            out[(rbase + r) * N_HID + sub] = val[r];
    }
}

// ---------------- edge scatter: out[dst] += w * table[src], 16 feats ----------------
// 4 threads per edge, float4 gather + 4 atomicAdds.
__global__ __launch_bounds__(256) void k_edge(const int* __restrict__ src,
                                              const int* __restrict__ dst,
                                              const float* __restrict__ ew,
                                              const float* __restrict__ tab,
                                              float* __restrict__ out) {
    int gid = blockIdx.x * 256 + threadIdx.x;
    int e = gid >> 2;
    if (e >= N_EDGES) return;
    int j4 = (gid & 3) << 2;
    int s = src[e];
    int d = dst[e];
    float w = ew[e];
    const float4 v = *(const float4*)&tab[s * N_HID + j4];
    float* o = &out[d * N_HID + j4];
    atomicAdd(o + 0, v.x * w);
    atomicAdd(o + 1, v.y * w);
    atomicAdd(o + 2, v.z * w);
    atomicAdd(o + 3, v.w * w);
}

// ---------------- h = relu(agg1 + b1), in place ----------------
__global__ void k_relu_bias(float* __restrict__ h, const float* __restrict__ b1) {
    int i = blockIdx.x * 256 + threadIdx.x;   // over N_NODES*4 float4s
    if (i >= N_NODES * 4) return;
    float4 v = ((float4*)h)[i];
    int jb = (i & 3) << 2;
    v.x = fmaxf(v.x + b1[jb + 0], 0.f);
    v.y = fmaxf(v.y + b1[jb + 1], 0.f);
    v.z = fmaxf(v.z + b1[jb + 2], 0.f);
    v.w = fmaxf(v.w + b1[jb + 3], 0.f);
    ((float4*)h)[i] = v;
}

// ---------------- out = log_softmax(agg2 @ W2 + b2) ----------------
// one wave per row; lanes 0..39 = classes.
__global__ __launch_bounds__(256) void k_out(const float* __restrict__ agg2,
                                             const float* __restrict__ W2,
                                             const float* __restrict__ b2,
                                             float* __restrict__ out) {
    int row  = (blockIdx.x * 256 + threadIdx.x) >> 6;
    int lane = threadIdx.x & 63;
    if (row >= N_NODES) return;

    const float* a = &agg2[row * N_HID];
    float av[16];
    #pragma unroll
    for (int k = 0; k < 16; k += 4) {
        float4 t = *(const float4*)&a[k];   // same addr across wave: broadcast
        av[k + 0] = t.x; av[k + 1] = t.y; av[k + 2] = t.z; av[k + 3] = t.w;
    }

    int c = (lane < N_CLS) ? lane : 0;
    float acc = b2[c];
    #pragma unroll
    for (int k = 0; k < 16; ++k)
        acc = fmaf(av[k], W2[k * N_CLS + c], acc);

    float mval = (lane < N_CLS) ? acc : -INFINITY;
    #pragma unroll
    for (int m = 32; m; m >>= 1) mval = fmaxf(mval, __shfl_xor(mval, m, 64));
    float ex = (lane < N_CLS) ? expf(acc - mval) : 0.f;
    float s = ex;
    #pragma unroll
    for (int m = 32; m; m >>= 1) s += __shfl_xor(s, m, 64);
    float ls = logf(s);
    if (lane < N_CLS) out[row * N_CLS + lane] = acc - mval - ls;
}

extern "C" void kernel_launch(void* const* d_in, const int* in_sizes, int n_in,
                              void* d_out, int out_size, void* d_ws, size_t ws_size,
                              hipStream_t stream) {
    const float* x    = (const float*)d_in[0];
    const int*   esrc = (const int*)  d_in[1];
    const int*   edst = (const int*)  d_in[2];
    const float* ew   = (const float*)d_in[3];
    const float* W1   = (const float*)d_in[4];
    const float* b1   = (const float*)d_in[5];
    const float* W2   = (const float*)d_in[6];
    const float* b2   = (const float*)d_in[7];
    float* out = (float*)d_out;

    float* buf0 = (float*)d_ws;                  // support1, later agg2
    float* buf1 = buf0 + (size_t)N_NODES * N_HID; // agg1 -> h

    const int n4 = N_NODES * 4;                  // float4 count of a [N,16] buffer
    const int zgrid = (n4 + 255) / 256;

    // agg1 = 0
    k_zero<<<zgrid, 256, 0, stream>>>((float4*)buf1, n4);
    // support1 = X @ W1
    k_gemm1<<<(N_NODES + 63) / 64, 256, 0, stream>>>(x, W1, buf0);
    // agg1 += scatter(support1)
    k_edge<<<(N_EDGES * 4 + 255) / 256, 256, 0, stream>>>(esrc, edst, ew, buf0, buf1);
    // h = relu(agg1 + b1)
    k_relu_bias<<<zgrid, 256, 0, stream>>>(buf1, b1);
    // agg2 = 0 (reuse buf0)
    k_zero<<<zgrid, 256, 0, stream>>>((float4*)buf0, n4);
    // agg2 += scatter(h)
    k_edge<<<(N_EDGES * 4 + 255) / 256, 256, 0, stream>>>(esrc, edst, ew, buf1, buf0);
    // out = log_softmax(agg2 @ W2 + b2)
    k_out<<<(N_NODES + 3) / 4, 256, 0, stream>>>(buf0, W2, b2, out);
}

// Round 4
// 942.828 us; speedup vs baseline: 1.9576x; 1.9576x over previous
//
#include <hip/hip_runtime.h>
#include <math.h>

#define N_NODES 100000
#define N_EDGES 3200000
#define N_FEAT  512
#define N_HID   16
#define N_CLS   40

#define CNT_PAD 100352          // N_NODES rounded up (alignment slack)
#define SCAN_BLK 4096           // elements scanned per block (256 thr * 16)
#define N_SCAN_BLKS 25          // ceil(100000/4096)

// ---------------- zero fill (float4) ----------------
__global__ void k_zero(float4* __restrict__ p, int n4) {
    int i = blockIdx.x * 256 + threadIdx.x;
    if (i < n4) p[i] = make_float4(0.f, 0.f, 0.f, 0.f);
}

// ---------------- zero fill (ints) ----------------
__global__ void k_zero_i(int* __restrict__ p, int n) {
    int i = blockIdx.x * 256 + threadIdx.x;
    if (i < n) p[i] = 0;
}

// ---------------- histogram of edge destinations ----------------
__global__ __launch_bounds__(256) void k_hist(const int* __restrict__ dst,
                                              int* __restrict__ cnt) {
    int e = blockIdx.x * 256 + threadIdx.x;
    if (e < N_EDGES) atomicAdd(&cnt[dst[e]], 1);
}

// ---------------- scan stage 1: per-block exclusive scan + block sums ----------------
__global__ __launch_bounds__(256) void k_scan1(const int* __restrict__ cnt,
                                               int* __restrict__ part,
                                               int* __restrict__ bsum) {
    __shared__ int sh[256];
    const int tid = threadIdx.x;
    const int base = blockIdx.x * SCAN_BLK + tid * 16;
    int v[16];
    int s = 0;
    #pragma unroll
    for (int i = 0; i < 16; ++i) {
        v[i] = (base + i < N_NODES) ? cnt[base + i] : 0;
        s += v[i];
    }
    sh[tid] = s;
    __syncthreads();
    // Hillis-Steele inclusive scan over 256 thread sums
    for (int off = 1; off < 256; off <<= 1) {
        int t = (tid >= off) ? sh[tid - off] : 0;
        __syncthreads();
        sh[tid] += t;
        __syncthreads();
    }
    int ex = (tid > 0) ? sh[tid - 1] : 0;   // exclusive prefix of this thread
    if (tid == 255) bsum[blockIdx.x] = sh[255];
    int run = ex;
    #pragma unroll
    for (int i = 0; i < 16; ++i) {
        if (base + i < N_NODES) part[base + i] = run;
        run += v[i];
    }
}

// ---------------- scan stage 2: exclusive scan of the 25 block sums ----------------
__global__ void k_scan2(const int* __restrict__ bsum, int* __restrict__ boffs) {
    if (threadIdx.x == 0) {
        int run = 0;
        for (int i = 0; i < N_SCAN_BLKS; ++i) { boffs[i] = run; run += bsum[i]; }
    }
}

// ---------------- scatter edges into CSR slots: srt[pos] = (src, w_bits) ----------------
__global__ __launch_bounds__(256) void k_scatter(const int* __restrict__ src,
                                                 const int* __restrict__ dst,
                                                 const float* __restrict__ ew,
                                                 const int* __restrict__ part,
                                                 const int* __restrict__ boffs,
                                                 int* __restrict__ cur,
                                                 int2* __restrict__ srt) {
    int e = blockIdx.x * 256 + threadIdx.x;
    if (e >= N_EDGES) return;
    int d = dst[e];
    int pos = part[d] + boffs[d >> 12] + atomicAdd(&cur[d], 1);
    srt[pos] = make_int2(src[e], __float_as_int(ew[e]));
}

// ---------------- CSR aggregation: out[n,j] = sum_{e: dst=n} w_e * tab[src_e, j] ----
// 16 lanes per node (lane = feature). 4-way unrolled edge loop for gather ILP.
// RELU=1 fuses out = relu(agg + bias).
template <int RELU>
__global__ __launch_bounds__(256) void k_agg(const int* __restrict__ part,
                                             const int* __restrict__ boffs,
                                             const int* __restrict__ cnt,
                                             const int2* __restrict__ srt,
                                             const float* __restrict__ tab,
                                             const float* __restrict__ bias,
                                             float* __restrict__ out) {
    int gid = blockIdx.x * 256 + threadIdx.x;
    int node = gid >> 4;
    int j = gid & 15;
    if (node >= N_NODES) return;
    int start = part[node] + boffs[node >> 12];
    int len = cnt[node];
    float a0 = 0.f, a1 = 0.f, a2 = 0.f, a3 = 0.f;
    int k = 0;
    for (; k + 4 <= len; k += 4) {
        int2 e0 = srt[start + k + 0];
        int2 e1 = srt[start + k + 1];
        int2 e2 = srt[start + k + 2];
        int2 e3 = srt[start + k + 3];
        a0 += __int_as_float(e0.y) * tab[e0.x * N_HID + j];
        a1 += __int_as_float(e1.y) * tab[e1.x * N_HID + j];
        a2 += __int_as_float(e2.y) * tab[e2.x * N_HID + j];
        a3 += __int_as_float(e3.y) * tab[e3.x * N_HID + j];
    }
    for (; k < len; ++k) {
        int2 e = srt[start + k];
        a0 += __int_as_float(e.y) * tab[e.x * N_HID + j];
    }
    float v = (a0 + a2) + (a1 + a3);
    if (RELU) v = fmaxf(v + bias[j], 0.f);
    out[node * N_HID + j] = v;
}

// ---------------- GEMM1: support1[N,16] = X[N,512] @ W1[512,16] ----------------
__global__ __launch_bounds__(256) void k_gemm1(const float* __restrict__ x,
                                               const float* __restrict__ W1,
                                               float* __restrict__ out) {
    __shared__ float W1T[16 * 512];
    const int tid = threadIdx.x;
    #pragma unroll
    for (int k = 0; k < 32; ++k) {
        int idx = tid + k * 256;          // 0..8191 over W1[512][16]
        int f = idx >> 4, j = idx & 15;
        W1T[j * 512 + f] = W1[idx];
    }
    __syncthreads();

    const int wave = tid >> 6;
    const int lane = tid & 63;
    const int q    = lane >> 4;
    const int sub  = lane & 15;
    const int rbase = blockIdx.x * 64 + wave * 16 + q * 4;

    float acc[4][16];
    #pragma unroll
    for (int r = 0; r < 4; ++r)
        #pragma unroll
        for (int j = 0; j < 16; ++j) acc[r][j] = 0.f;

    #pragma unroll
    for (int i = 0; i < 8; ++i) {
        const int f = i * 64 + sub * 4;
        float4 v[4];
        #pragma unroll
        for (int r = 0; r < 4; ++r) {
            if (rbase + r < N_NODES)
                v[r] = *(const float4*)&x[(size_t)(rbase + r) * N_FEAT + f];
            else
                v[r] = make_float4(0.f, 0.f, 0.f, 0.f);
        }
        #pragma unroll
        for (int j = 0; j < 16; ++j) {
            const float4 w4 = *(const float4*)&W1T[j * 512 + f];
            #pragma unroll
            for (int r = 0; r < 4; ++r) {
                acc[r][j] += v[r].x * w4.x + v[r].y * w4.y
                           + v[r].z * w4.z + v[r].w * w4.w;
            }
        }
    }

    #pragma unroll
    for (int m = 1; m <= 8; m <<= 1) {
        #pragma unroll
        for (int r = 0; r < 4; ++r)
            #pragma unroll
            for (int j = 0; j < 16; ++j)
                acc[r][j] += __shfl_xor(acc[r][j], m, 64);
    }

    float val[4];
    #pragma unroll
    for (int r = 0; r < 4; ++r) val[r] = acc[r][0];
    #pragma unroll
    for (int j = 1; j < 16; ++j) {
        #pragma unroll
        for (int r = 0; r < 4; ++r)
            val[r] = (sub == j) ? acc[r][j] : val[r];
    }
    #pragma unroll
    for (int r = 0; r < 4; ++r) {
        if (rbase + r < N_NODES)
            out[(rbase + r) * N_HID + sub] = val[r];
    }
}

// ---------------- fallback path kernels (atomic scatter) ----------------
__global__ __launch_bounds__(256) void k_edge(const int* __restrict__ src,
                                              const int* __restrict__ dst,
                                              const float* __restrict__ ew,
                                              const float* __restrict__ tab,
                                              float* __restrict__ out) {
    int gid = blockIdx.x * 256 + threadIdx.x;
    int e = gid >> 2;
    if (e >= N_EDGES) return;
    int j4 = (gid & 3) << 2;
    int s = src[e];
    int d = dst[e];
    float w = ew[e];
    const float4 v = *(const float4*)&tab[s * N_HID + j4];
    float* o = &out[d * N_HID + j4];
    atomicAdd(o + 0, v.x * w);
    atomicAdd(o + 1, v.y * w);
    atomicAdd(o + 2, v.z * w);
    atomicAdd(o + 3, v.w * w);
}

__global__ void k_relu_bias(float* __restrict__ h, const float* __restrict__ b1) {
    int i = blockIdx.x * 256 + threadIdx.x;
    if (i >= N_NODES * 4) return;
    float4 v = ((float4*)h)[i];
    int jb = (i & 3) << 2;
    v.x = fmaxf(v.x + b1[jb + 0], 0.f);
    v.y = fmaxf(v.y + b1[jb + 1], 0.f);
    v.z = fmaxf(v.z + b1[jb + 2], 0.f);
    v.w = fmaxf(v.w + b1[jb + 3], 0.f);
    ((float4*)h)[i] = v;
}

// ---------------- out = log_softmax(agg2 @ W2 + b2) ----------------
__global__ __launch_bounds__(256) void k_out(const float* __restrict__ agg2,
                                             const float* __restrict__ W2,
                                             const float* __restrict__ b2,
                                             float* __restrict__ out) {
    int row  = (blockIdx.x * 256 + threadIdx.x) >> 6;
    int lane = threadIdx.x & 63;
    if (row >= N_NODES) return;

    const float* a = &agg2[row * N_HID];
    float av[16];
    #pragma unroll
    for (int k = 0; k < 16; k += 4) {
        float4 t = *(const float4*)&a[k];
        av[k + 0] = t.x; av[k + 1] = t.y; av[k + 2] = t.z; av[k + 3] = t.w;
    }

    int c = (lane < N_CLS) ? lane : 0;
    float acc = b2[c];
    #pragma unroll
    for (int k = 0; k < 16; ++k)
        acc = fmaf(av[k], W2[k * N_CLS + c], acc);

    float mval = (lane < N_CLS) ? acc : -INFINITY;
    #pragma unroll
    for (int m = 32; m; m >>= 1) mval = fmaxf(mval, __shfl_xor(mval, m, 64));
    float ex = (lane < N_CLS) ? expf(acc - mval) : 0.f;
    float s = ex;
    #pragma unroll
    for (int m = 32; m; m >>= 1) s += __shfl_xor(s, m, 64);
    float ls = logf(s);
    if (lane < N_CLS) out[row * N_CLS + lane] = acc - mval - ls;
}

extern "C" void kernel_launch(void* const* d_in, const int* in_sizes, int n_in,
                              void* d_out, int out_size, void* d_ws, size_t ws_size,
                              hipStream_t stream) {
    const float* x    = (const float*)d_in[0];
    const int*   esrc = (const int*)  d_in[1];
    const int*   edst = (const int*)  d_in[2];
    const float* ew   = (const float*)d_in[3];
    const float* W1   = (const float*)d_in[4];
    const float* b1   = (const float*)d_in[5];
    const float* W2   = (const float*)d_in[6];
    const float* b2   = (const float*)d_in[7];
    float* out = (float*)d_out;

    // ---- workspace layout (4-byte units) ----
    // srt   : [0, 2*N_EDGES)              int2 packed (src, w_bits)  25.6 MB
    // buf0  : support1 / agg2             1.6M floats                 6.4 MB
    // buf1  : h                           1.6M floats                 6.4 MB
    // cnt, cur, part : CNT_PAD ints each                              1.2 MB
    // bsum, boffs    : 64 ints each
    int* ws = (int*)d_ws;
    int2*  srt  = (int2*)ws;
    float* buf0 = (float*)(ws + 2 * (size_t)N_EDGES);
    float* buf1 = buf0 + (size_t)N_NODES * N_HID;
    int*   cnt  = (int*)(buf1 + (size_t)N_NODES * N_HID);
    int*   cur  = cnt + CNT_PAD;
    int*   part = cur + CNT_PAD;
    int*   bsum = part + CNT_PAD;
    int*   boffs = bsum + 64;
    const size_t need = ((size_t)(boffs + 64) - (size_t)d_ws);

    const int n4 = N_NODES * 4;
    const int zgrid = (n4 + 255) / 256;
    const int egrid = (N_EDGES + 255) / 256;

    if (ws_size >= need) {
        // ---- CSR path ----
        // zero cnt + cur (contiguous)
        k_zero_i<<<(2 * CNT_PAD + 255) / 256, 256, 0, stream>>>(cnt, 2 * CNT_PAD);
        // histogram of destinations
        k_hist<<<egrid, 256, 0, stream>>>(edst, cnt);
        // exclusive scan -> part (+ boffs per 4096-chunk)
        k_scan1<<<N_SCAN_BLKS, 256, 0, stream>>>(cnt, part, bsum);
        k_scan2<<<1, 64, 0, stream>>>(bsum, boffs);
        // scatter (src, w) pairs into CSR order
        k_scatter<<<egrid, 256, 0, stream>>>(esrc, edst, ew, part, boffs, cur, srt);
        // support1 = X @ W1
        k_gemm1<<<(N_NODES + 63) / 64, 256, 0, stream>>>(x, W1, buf0);
        // h = relu(agg(support1) + b1)   (fused)
        k_agg<1><<<(N_NODES * 16 + 255) / 256, 256, 0, stream>>>(
            part, boffs, cnt, srt, buf0, b1, buf1);
        // agg2 = agg(h)
        k_agg<0><<<(N_NODES * 16 + 255) / 256, 256, 0, stream>>>(
            part, boffs, cnt, srt, buf1, b1 /*unused*/, buf0);
        // out = log_softmax(agg2 @ W2 + b2)
        k_out<<<(N_NODES + 3) / 4, 256, 0, stream>>>(buf0, W2, b2, out);
    } else {
        // ---- fallback: original atomic path (needs only buf0+buf1) ----
        float* fb0 = (float*)d_ws;
        float* fb1 = fb0 + (size_t)N_NODES * N_HID;
        k_zero<<<zgrid, 256, 0, stream>>>((float4*)fb1, n4);
        k_gemm1<<<(N_NODES + 63) / 64, 256, 0, stream>>>(x, W1, fb0);
        k_edge<<<(N_EDGES * 4 + 255) / 256, 256, 0, stream>>>(esrc, edst, ew, fb0, fb1);
        k_relu_bias<<<zgrid, 256, 0, stream>>>(fb1, b1);
        k_zero<<<zgrid, 256, 0, stream>>>((float4*)fb0, n4);
        k_edge<<<(N_EDGES * 4 + 255) / 256, 256, 0, stream>>>(esrc, edst, ew, fb1, fb0);
        k_out<<<(N_NODES + 3) / 4, 256, 0, stream>>>(fb0, W2, b2, out);
    }
}

// Round 5
// 727.803 us; speedup vs baseline: 2.5359x; 1.2954x over previous
//
#include <hip/hip_runtime.h>
#include <math.h>

#define N_NODES 100000
#define N_EDGES 3200000
#define N_FEAT  512
#define N_HID   16
#define N_CLS   40

#define CNT_PAD 100352          // N_NODES rounded up (alignment slack)
#define SCAN_BLK 4096           // elements scanned per block (256 thr * 16)
#define N_SCAN_BLKS 25          // ceil(100000/4096)

// ---------------- zero fill (float4) ----------------
__global__ void k_zero(float4* __restrict__ p, int n4) {
    int i = blockIdx.x * 256 + threadIdx.x;
    if (i < n4) p[i] = make_float4(0.f, 0.f, 0.f, 0.f);
}

// ---------------- zero fill (ints) ----------------
__global__ void k_zero_i(int* __restrict__ p, int n) {
    int i = blockIdx.x * 256 + threadIdx.x;
    if (i < n) p[i] = 0;
}

// ---------------- histogram of edge destinations ----------------
__global__ __launch_bounds__(256) void k_hist(const int* __restrict__ dst,
                                              int* __restrict__ cnt) {
    int e = blockIdx.x * 256 + threadIdx.x;
    if (e < N_EDGES) atomicAdd(&cnt[dst[e]], 1);
}

// ---------------- scan stage 1: per-block exclusive scan + block sums ----------------
__global__ __launch_bounds__(256) void k_scan1(const int* __restrict__ cnt,
                                               int* __restrict__ part,
                                               int* __restrict__ bsum) {
    __shared__ int sh[256];
    const int tid = threadIdx.x;
    const int base = blockIdx.x * SCAN_BLK + tid * 16;
    int v[16];
    int s = 0;
    #pragma unroll
    for (int i = 0; i < 16; ++i) {
        v[i] = (base + i < N_NODES) ? cnt[base + i] : 0;
        s += v[i];
    }
    sh[tid] = s;
    __syncthreads();
    // Hillis-Steele inclusive scan over 256 thread sums
    for (int off = 1; off < 256; off <<= 1) {
        int t = (tid >= off) ? sh[tid - off] : 0;
        __syncthreads();
        sh[tid] += t;
        __syncthreads();
    }
    int ex = (tid > 0) ? sh[tid - 1] : 0;   // exclusive prefix of this thread
    if (tid == 255) bsum[blockIdx.x] = sh[255];
    int run = ex;
    #pragma unroll
    for (int i = 0; i < 16; ++i) {
        if (base + i < N_NODES) part[base + i] = run;
        run += v[i];
    }
}

// ---------------- scan stage 2: exclusive scan of the 25 block sums ----------------
__global__ void k_scan2(const int* __restrict__ bsum, int* __restrict__ boffs) {
    if (threadIdx.x == 0) {
        int run = 0;
        for (int i = 0; i < N_SCAN_BLKS; ++i) { boffs[i] = run; run += bsum[i]; }
    }
}

// ---------------- scatter edges into CSR slots: srt[pos] = (src, w_bits) ----------------
__global__ __launch_bounds__(256) void k_scatter(const int* __restrict__ src,
                                                 const int* __restrict__ dst,
                                                 const float* __restrict__ ew,
                                                 const int* __restrict__ part,
                                                 const int* __restrict__ boffs,
                                                 int* __restrict__ cur,
                                                 int2* __restrict__ srt) {
    int e = blockIdx.x * 256 + threadIdx.x;
    if (e >= N_EDGES) return;
    int d = dst[e];
    int pos = part[d] + boffs[d >> 12] + atomicAdd(&cur[d], 1);
    srt[pos] = make_int2(src[e], __float_as_int(ew[e]));
}

// ---------------- CSR aggregation: out[n,j] = sum_{e: dst=n} w_e * tab[src_e, j] ----
// 16 lanes per node (lane = feature). 4-way unrolled edge loop for gather ILP.
// RELU=1 fuses out = relu(agg + bias).
template <int RELU>
__global__ __launch_bounds__(256) void k_agg(const int* __restrict__ part,
                                             const int* __restrict__ boffs,
                                             const int* __restrict__ cnt,
                                             const int2* __restrict__ srt,
                                             const float* __restrict__ tab,
                                             const float* __restrict__ bias,
                                             float* __restrict__ out) {
    int gid = blockIdx.x * 256 + threadIdx.x;
    int node = gid >> 4;
    int j = gid & 15;
    if (node >= N_NODES) return;
    int start = part[node] + boffs[node >> 12];
    int len = cnt[node];
    float a0 = 0.f, a1 = 0.f, a2 = 0.f, a3 = 0.f;
    int k = 0;
    for (; k + 4 <= len; k += 4) {
        int2 e0 = srt[start + k + 0];
        int2 e1 = srt[start + k + 1];
        int2 e2 = srt[start + k + 2];
        int2 e3 = srt[start + k + 3];
        a0 += __int_as_float(e0.y) * tab[e0.x * N_HID + j];
        a1 += __int_as_float(e1.y) * tab[e1.x * N_HID + j];
        a2 += __int_as_float(e2.y) * tab[e2.x * N_HID + j];
        a3 += __int_as_float(e3.y) * tab[e3.x * N_HID + j];
    }
    for (; k < len; ++k) {
        int2 e = srt[start + k];
        a0 += __int_as_float(e.y) * tab[e.x * N_HID + j];
    }
    float v = (a0 + a2) + (a1 + a3);
    if (RELU) v = fmaxf(v + bias[j], 0.f);
    out[node * N_HID + j] = v;
}

// ---------------- GEMM1: support1[N,16] = X[N,512] @ W1[512,16] ----------------
// v2: quarter-wave (16 lanes) per 4 rows, k split across the 16 lanes.
// acc = 4 named float[16] arrays (static indexing only -> registers).
// W1 in LDS with 2-bit XOR quad swizzle: quad j4 of row k lives at slot
// j4 ^ ((k>>2)&3). ds_read_b128-aligned; 4-way bank conflict (1.58x, ok).
// #pragma unroll 1 on the K-chunk loop: prevents the 8x load-hoist that
// blew VGPRs to 256 + scratch spills (265 MB WRITE_SIZE) in v1.
#define FMA16(A, F, W0, W1v, W2v, W3v)                                   \
    A[0] += F * W0.x;  A[1] += F * W0.y;  A[2]  += F * W0.z;  A[3]  += F * W0.w;  \
    A[4] += F * W1v.x; A[5] += F * W1v.y; A[6]  += F * W1v.z; A[7]  += F * W1v.w; \
    A[8] += F * W2v.x; A[9] += F * W2v.y; A[10] += F * W2v.z; A[11] += F * W2v.w; \
    A[12]+= F * W3v.x; A[13]+= F * W3v.y; A[14] += F * W3v.z; A[15] += F * W3v.w;

__global__ __launch_bounds__(256) void k_gemm1(const float* __restrict__ x,
                                               const float* __restrict__ W1,
                                               float* __restrict__ out) {
    __shared__ float Wl[512 * 16];
    const int tid = threadIdx.x;
    #pragma unroll
    for (int u = 0; u < 32; ++u) {
        int idx = tid + u * 256;          // over W1[512][16]
        int k = idx >> 4, j = idx & 15;
        int slot = (j >> 2) ^ ((k >> 2) & 3);
        Wl[k * 16 + slot * 4 + (j & 3)] = W1[idx];
    }
    __syncthreads();

    const int sub  = tid & 15;            // k-slice owner within quarter-wave
    const int grp  = tid >> 4;            // 0..15: quarter-wave id in block
    const int rbase = blockIdx.x * 64 + grp * 4;

    const int r0 = min(rbase + 0, N_NODES - 1);
    const int r1 = min(rbase + 1, N_NODES - 1);
    const int r2 = min(rbase + 2, N_NODES - 1);
    const int r3 = min(rbase + 3, N_NODES - 1);
    const float* xp0 = x + (size_t)r0 * N_FEAT + sub * 4;
    const float* xp1 = x + (size_t)r1 * N_FEAT + sub * 4;
    const float* xp2 = x + (size_t)r2 * N_FEAT + sub * 4;
    const float* xp3 = x + (size_t)r3 * N_FEAT + sub * 4;

    float a0[16], a1[16], a2[16], a3[16];
    #pragma unroll
    for (int j = 0; j < 16; ++j) { a0[j] = 0.f; a1[j] = 0.f; a2[j] = 0.f; a3[j] = 0.f; }

    const int sw = sub & 3;               // = (k>>2)&3 for this lane's k's

    #pragma unroll 1
    for (int i = 0; i < 8; ++i) {
        const float4 xa = *(const float4*)(xp0 + i * 64);
        const float4 xb = *(const float4*)(xp1 + i * 64);
        const float4 xc = *(const float4*)(xp2 + i * 64);
        const float4 xd = *(const float4*)(xp3 + i * 64);
        const int kb = i * 64 + sub * 4;
        #pragma unroll
        for (int t = 0; t < 4; ++t) {
            const float* wr = &Wl[(kb + t) * 16];
            const float4 w0 = *(const float4*)(wr + ((0 ^ sw) << 2));
            const float4 w1 = *(const float4*)(wr + ((1 ^ sw) << 2));
            const float4 w2 = *(const float4*)(wr + ((2 ^ sw) << 2));
            const float4 w3 = *(const float4*)(wr + ((3 ^ sw) << 2));
            const float fa = (t == 0) ? xa.x : (t == 1) ? xa.y : (t == 2) ? xa.z : xa.w;
            const float fb = (t == 0) ? xb.x : (t == 1) ? xb.y : (t == 2) ? xb.z : xb.w;
            const float fc = (t == 0) ? xc.x : (t == 1) ? xc.y : (t == 2) ? xc.z : xc.w;
            const float fd = (t == 0) ? xd.x : (t == 1) ? xd.y : (t == 2) ? xd.z : xd.w;
            FMA16(a0, fa, w0, w1, w2, w3)
            FMA16(a1, fb, w0, w1, w2, w3)
            FMA16(a2, fc, w0, w1, w2, w3)
            FMA16(a3, fd, w0, w1, w2, w3)
        }
    }

    // butterfly reduce over the 16-lane group (xor bits 0..3 of lane)
    #pragma unroll
    for (int m = 1; m <= 8; m <<= 1) {
        #pragma unroll
        for (int j = 0; j < 16; ++j) {
            a0[j] += __shfl_xor(a0[j], m, 64);
            a1[j] += __shfl_xor(a1[j], m, 64);
            a2[j] += __shfl_xor(a2[j], m, 64);
            a3[j] += __shfl_xor(a3[j], m, 64);
        }
    }

    // lane `sub` writes column j = sub of its 4 rows (static-index select)
    float v0 = a0[0], v1 = a1[0], v2 = a2[0], v3 = a3[0];
    #pragma unroll
    for (int j = 1; j < 16; ++j) {
        const bool p = (sub == j);
        v0 = p ? a0[j] : v0;
        v1 = p ? a1[j] : v1;
        v2 = p ? a2[j] : v2;
        v3 = p ? a3[j] : v3;
    }
    if (rbase + 0 < N_NODES) out[(rbase + 0) * N_HID + sub] = v0;
    if (rbase + 1 < N_NODES) out[(rbase + 1) * N_HID + sub] = v1;
    if (rbase + 2 < N_NODES) out[(rbase + 2) * N_HID + sub] = v2;
    if (rbase + 3 < N_NODES) out[(rbase + 3) * N_HID + sub] = v3;
}

// ---------------- fallback path kernels (atomic scatter) ----------------
__global__ __launch_bounds__(256) void k_edge(const int* __restrict__ src,
                                              const int* __restrict__ dst,
                                              const float* __restrict__ ew,
                                              const float* __restrict__ tab,
                                              float* __restrict__ out) {
    int gid = blockIdx.x * 256 + threadIdx.x;
    int e = gid >> 2;
    if (e >= N_EDGES) return;
    int j4 = (gid & 3) << 2;
    int s = src[e];
    int d = dst[e];
    float w = ew[e];
    const float4 v = *(const float4*)&tab[s * N_HID + j4];
    float* o = &out[d * N_HID + j4];
    atomicAdd(o + 0, v.x * w);
    atomicAdd(o + 1, v.y * w);
    atomicAdd(o + 2, v.z * w);
    atomicAdd(o + 3, v.w * w);
}

__global__ void k_relu_bias(float* __restrict__ h, const float* __restrict__ b1) {
    int i = blockIdx.x * 256 + threadIdx.x;
    if (i >= N_NODES * 4) return;
    float4 v = ((float4*)h)[i];
    int jb = (i & 3) << 2;
    v.x = fmaxf(v.x + b1[jb + 0], 0.f);
    v.y = fmaxf(v.y + b1[jb + 1], 0.f);
    v.z = fmaxf(v.z + b1[jb + 2], 0.f);
    v.w = fmaxf(v.w + b1[jb + 3], 0.f);
    ((float4*)h)[i] = v;
}

// ---------------- out = log_softmax(agg2 @ W2 + b2) ----------------
__global__ __launch_bounds__(256) void k_out(const float* __restrict__ agg2,
                                             const float* __restrict__ W2,
                                             const float* __restrict__ b2,
                                             float* __restrict__ out) {
    int row  = (blockIdx.x * 256 + threadIdx.x) >> 6;
    int lane = threadIdx.x & 63;
    if (row >= N_NODES) return;

    const float* a = &agg2[row * N_HID];
    float av[16];
    #pragma unroll
    for (int k = 0; k < 16; k += 4) {
        float4 t = *(const float4*)&a[k];
        av[k + 0] = t.x; av[k + 1] = t.y; av[k + 2] = t.z; av[k + 3] = t.w;
    }

    int c = (lane < N_CLS) ? lane : 0;
    float acc = b2[c];
    #pragma unroll
    for (int k = 0; k < 16; ++k)
        acc = fmaf(av[k], W2[k * N_CLS + c], acc);

    float mval = (lane < N_CLS) ? acc : -INFINITY;
    #pragma unroll
    for (int m = 32; m; m >>= 1) mval = fmaxf(mval, __shfl_xor(mval, m, 64));
    float ex = (lane < N_CLS) ? expf(acc - mval) : 0.f;
    float s = ex;
    #pragma unroll
    for (int m = 32; m; m >>= 1) s += __shfl_xor(s, m, 64);
    float ls = logf(s);
    if (lane < N_CLS) out[row * N_CLS + lane] = acc - mval - ls;
}

extern "C" void kernel_launch(void* const* d_in, const int* in_sizes, int n_in,
                              void* d_out, int out_size, void* d_ws, size_t ws_size,
                              hipStream_t stream) {
    const float* x    = (const float*)d_in[0];
    const int*   esrc = (const int*)  d_in[1];
    const int*   edst = (const int*)  d_in[2];
    const float* ew   = (const float*)d_in[3];
    const float* W1   = (const float*)d_in[4];
    const float* b1   = (const float*)d_in[5];
    const float* W2   = (const float*)d_in[6];
    const float* b2   = (const float*)d_in[7];
    float* out = (float*)d_out;

    // ---- workspace layout (4-byte units) ----
    // srt   : [0, 2*N_EDGES)              int2 packed (src, w_bits)  25.6 MB
    // buf0  : support1 / agg2             1.6M floats                 6.4 MB
    // buf1  : h                           1.6M floats                 6.4 MB
    // cnt, cur, part : CNT_PAD ints each                              1.2 MB
    // bsum, boffs    : 64 ints each
    int* ws = (int*)d_ws;
    int2*  srt  = (int2*)ws;
    float* buf0 = (float*)(ws + 2 * (size_t)N_EDGES);
    float* buf1 = buf0 + (size_t)N_NODES * N_HID;
    int*   cnt  = (int*)(buf1 + (size_t)N_NODES * N_HID);
    int*   cur  = cnt + CNT_PAD;
    int*   part = cur + CNT_PAD;
    int*   bsum = part + CNT_PAD;
    int*   boffs = bsum + 64;
    const size_t need = ((size_t)(boffs + 64) - (size_t)d_ws);

    const int n4 = N_NODES * 4;
    const int zgrid = (n4 + 255) / 256;
    const int egrid = (N_EDGES + 255) / 256;

    if (ws_size >= need) {
        // ---- CSR path ----
        k_zero_i<<<(2 * CNT_PAD + 255) / 256, 256, 0, stream>>>(cnt, 2 * CNT_PAD);
        k_hist<<<egrid, 256, 0, stream>>>(edst, cnt);
        k_scan1<<<N_SCAN_BLKS, 256, 0, stream>>>(cnt, part, bsum);
        k_scan2<<<1, 64, 0, stream>>>(bsum, boffs);
        k_scatter<<<egrid, 256, 0, stream>>>(esrc, edst, ew, part, boffs, cur, srt);
        // support1 = X @ W1   (64 rows per 256-thread block)
        k_gemm1<<<(N_NODES + 63) / 64, 256, 0, stream>>>(x, W1, buf0);
        // h = relu(agg(support1) + b1)   (fused)
        k_agg<1><<<(N_NODES * 16 + 255) / 256, 256, 0, stream>>>(
            part, boffs, cnt, srt, buf0, b1, buf1);
        // agg2 = agg(h)
        k_agg<0><<<(N_NODES * 16 + 255) / 256, 256, 0, stream>>>(
            part, boffs, cnt, srt, buf1, b1 /*unused*/, buf0);
        // out = log_softmax(agg2 @ W2 + b2)
        k_out<<<(N_NODES + 3) / 4, 256, 0, stream>>>(buf0, W2, b2, out);
    } else {
        // ---- fallback: original atomic path (needs only buf0+buf1) ----
        float* fb0 = (float*)d_ws;
        float* fb1 = fb0 + (size_t)N_NODES * N_HID;
        k_zero<<<zgrid, 256, 0, stream>>>((float4*)fb1, n4);
        k_gemm1<<<(N_NODES + 63) / 64, 256, 0, stream>>>(x, W1, fb0);
        k_edge<<<(N_EDGES * 4 + 255) / 256, 256, 0, stream>>>(esrc, edst, ew, fb0, fb1);
        k_relu_bias<<<zgrid, 256, 0, stream>>>(fb1, b1);
        k_zero<<<zgrid, 256, 0, stream>>>((float4*)fb0, n4);
        k_edge<<<(N_EDGES * 4 + 255) / 256, 256, 0, stream>>>(esrc, edst, ew, fb1, fb0);
        k_out<<<(N_NODES + 3) / 4, 256, 0, stream>>>(fb0, W2, b2, out);
    }
}

// Round 7
// 694.721 us; speedup vs baseline: 2.6567x; 1.0476x over previous
//
#include <hip/hip_runtime.h>
#include <math.h>

#define N_NODES 100000
#define N_EDGES 3200000
#define N_FEAT  512
#define N_HID   16
#define N_CLS   40

#define CNT_PAD 100352          // N_NODES rounded up (alignment slack)
#define SCAN_BLK 4096           // elements scanned per block (256 thr * 16)
#define N_SCAN_BLKS 25          // ceil(100000/4096)

#define BUCKET_SHIFT 9          // 512 nodes per bucket
#define NB 196                  // ceil(100000/512)
#define NB_PAD 256
#define BIN_CHUNK 4096          // edges per k_bin block (16 per thread)

// ---------------- zero fill (float4) ----------------
__global__ void k_zero(float4* __restrict__ p, int n4) {
    int i = blockIdx.x * 256 + threadIdx.x;
    if (i < n4) p[i] = make_float4(0.f, 0.f, 0.f, 0.f);
}

// ---------------- zero fill (ints) ----------------
__global__ void k_zero_i(int* __restrict__ p, int n) {
    int i = blockIdx.x * 256 + threadIdx.x;
    if (i < n) p[i] = 0;
}

// ---------------- histogram of edge destinations ----------------
__global__ __launch_bounds__(256) void k_hist(const int* __restrict__ dst,
                                              int* __restrict__ cnt) {
    int e = blockIdx.x * 256 + threadIdx.x;
    if (e < N_EDGES) atomicAdd(&cnt[dst[e]], 1);
}

// ---------------- scan stage 1: per-block exclusive scan + block sums ----------------
__global__ __launch_bounds__(256) void k_scan1(const int* __restrict__ cnt,
                                               int* __restrict__ part,
                                               int* __restrict__ bsum) {
    __shared__ int sh[256];
    const int tid = threadIdx.x;
    const int base = blockIdx.x * SCAN_BLK + tid * 16;
    int v[16];
    int s = 0;
    #pragma unroll
    for (int i = 0; i < 16; ++i) {
        v[i] = (base + i < N_NODES) ? cnt[base + i] : 0;
        s += v[i];
    }
    sh[tid] = s;
    __syncthreads();
    // Hillis-Steele inclusive scan over 256 thread sums
    for (int off = 1; off < 256; off <<= 1) {
        int t = (tid >= off) ? sh[tid - off] : 0;
        __syncthreads();
        sh[tid] += t;
        __syncthreads();
    }
    int ex = (tid > 0) ? sh[tid - 1] : 0;   // exclusive prefix of this thread
    if (tid == 255) bsum[blockIdx.x] = sh[255];
    int run = ex;
    #pragma unroll
    for (int i = 0; i < 16; ++i) {
        if (base + i < N_NODES) part[base + i] = run;
        run += v[i];
    }
}

// ---------------- scan stage 2: scan block sums + derive bucket offsets ----------------
// boffs[i]: exclusive scan of the 25 scan-block sums.
// offb[b] : CSR start of bucket b's first node (= bin-buffer region start);
//           offb[NB] = N_EDGES.
__global__ void k_scan2(const int* __restrict__ bsum, int* __restrict__ boffs,
                        const int* __restrict__ part, int* __restrict__ offb) {
    if (threadIdx.x == 0) {
        int run = 0;
        for (int i = 0; i < N_SCAN_BLKS; ++i) { boffs[i] = run; run += bsum[i]; }
    }
    __syncthreads();
    for (int b = threadIdx.x; b <= NB; b += 64) {
        if (b == NB) {
            offb[b] = N_EDGES;
        } else {
            int node0 = b << BUCKET_SHIFT;
            offb[b] = part[node0] + boffs[node0 >> 12];
        }
    }
}

// ---------------- pass A: bin edges by dst bucket (dense per-bucket runs) ----------
// Per block: LDS count -> one global ticket per touched bucket -> clustered writes.
// Record packs (src | dstlo<<17, w_bits): src<2^17, dstlo<2^9.
__global__ __launch_bounds__(256) void k_bin(const int* __restrict__ src,
                                             const int* __restrict__ dst,
                                             const float* __restrict__ ew,
                                             const int* __restrict__ offb,
                                             int* __restrict__ curb,
                                             int2* __restrict__ bin) {
    __shared__ int lcnt[NB];
    __shared__ int lbase[NB];
    const int tid = threadIdx.x;
    const int e0 = blockIdx.x * BIN_CHUNK;
    if (tid < NB) lcnt[tid] = 0;
    __syncthreads();
    // phase 1: local bucket histogram
    #pragma unroll
    for (int u = 0; u < 16; ++u) {
        int e = e0 + u * 256 + tid;
        if (e < N_EDGES) atomicAdd(&lcnt[dst[e] >> BUCKET_SHIFT], 1);
    }
    __syncthreads();
    // phase 2: reserve a contiguous global range per bucket
    if (tid < NB) {
        int c = lcnt[tid];
        lbase[tid] = (c > 0) ? (offb[tid] + atomicAdd(&curb[tid], c)) : 0;
        lcnt[tid] = 0;
    }
    __syncthreads();
    // phase 3: write records into the reserved runs
    #pragma unroll
    for (int u = 0; u < 16; ++u) {
        int e = e0 + u * 256 + tid;
        if (e < N_EDGES) {
            int d = dst[e];
            int b = d >> BUCKET_SHIFT;
            int rank = atomicAdd(&lcnt[b], 1);
            bin[lbase[b] + rank] =
                make_int2(src[e] | ((d & 511) << 17), __float_as_int(ew[e]));
        }
    }
}

// ---------------- pass B: place bin records into CSR slots ----------------
// One block per bucket; srt window per bucket ~131 KB (L2-resident), so
// lines fill fully before eviction (writeback ~= buffer size, not 8x).
__global__ __launch_bounds__(256) void k_place(const int* __restrict__ part,
                                               const int* __restrict__ boffs,
                                               const int* __restrict__ offb,
                                               const int2* __restrict__ bin,
                                               int2* __restrict__ srt) {
    __shared__ int lcur[512];
    const int b = blockIdx.x;
    const int tid = threadIdx.x;
    lcur[tid] = 0;
    lcur[tid + 256] = 0;
    __syncthreads();
    const int beg = offb[b], end = offb[b + 1];
    for (int i = beg + tid; i < end; i += 256) {
        int2 rec = bin[i];
        int dlo = (rec.x >> 17) & 511;
        int s = rec.x & 0x1FFFF;
        int d = (b << BUCKET_SHIFT) + dlo;
        int rank = atomicAdd(&lcur[dlo], 1);
        int pos = part[d] + boffs[d >> 12] + rank;
        srt[pos] = make_int2(s, rec.y);
    }
}

// ---------------- CSR aggregation: out[n,j] = sum_{e: dst=n} w_e * tab[src_e, j] ----
// 16 lanes per node (lane = feature). 4-way unrolled edge loop for gather ILP.
// RELU=1 fuses out = relu(agg + bias).
template <int RELU>
__global__ __launch_bounds__(256) void k_agg(const int* __restrict__ part,
                                             const int* __restrict__ boffs,
                                             const int* __restrict__ cnt,
                                             const int2* __restrict__ srt,
                                             const float* __restrict__ tab,
                                             const float* __restrict__ bias,
                                             float* __restrict__ out) {
    int gid = blockIdx.x * 256 + threadIdx.x;
    int node = gid >> 4;
    int j = gid & 15;
    if (node >= N_NODES) return;
    int start = part[node] + boffs[node >> 12];
    int len = cnt[node];
    float a0 = 0.f, a1 = 0.f, a2 = 0.f, a3 = 0.f;
    int k = 0;
    for (; k + 4 <= len; k += 4) {
        int2 e0 = srt[start + k + 0];
        int2 e1 = srt[start + k + 1];
        int2 e2 = srt[start + k + 2];
        int2 e3 = srt[start + k + 3];
        a0 += __int_as_float(e0.y) * tab[e0.x * N_HID + j];
        a1 += __int_as_float(e1.y) * tab[e1.x * N_HID + j];
        a2 += __int_as_float(e2.y) * tab[e2.x * N_HID + j];
        a3 += __int_as_float(e3.y) * tab[e3.x * N_HID + j];
    }
    for (; k < len; ++k) {
        int2 e = srt[start + k];
        a0 += __int_as_float(e.y) * tab[e.x * N_HID + j];
    }
    float v = (a0 + a2) + (a1 + a3);
    if (RELU) v = fmaxf(v + bias[j], 0.f);
    out[node * N_HID + j] = v;
}

// ---------------- GEMM1: support1[N,16] = X[N,512] @ W1[512,16] ----------------
// v2: quarter-wave (16 lanes) per 4 rows, k split across the 16 lanes.
// #pragma unroll 1 on the K-chunk loop prevents the load-hoist VGPR blowup.
#define FMA16(A, F, W0, W1v, W2v, W3v)                                   \
    A[0] += F * W0.x;  A[1] += F * W0.y;  A[2]  += F * W0.z;  A[3]  += F * W0.w;  \
    A[4] += F * W1v.x; A[5] += F * W1v.y; A[6]  += F * W1v.z; A[7]  += F * W1v.w; \
    A[8] += F * W2v.x; A[9] += F * W2v.y; A[10] += F * W2v.z; A[11] += F * W2v.w; \
    A[12]+= F * W3v.x; A[13]+= F * W3v.y; A[14] += F * W3v.z; A[15] += F * W3v.w;

__global__ __launch_bounds__(256) void k_gemm1(const float* __restrict__ x,
                                               const float* __restrict__ W1,
                                               float* __restrict__ out) {
    __shared__ float Wl[512 * 16];
    const int tid = threadIdx.x;
    #pragma unroll
    for (int u = 0; u < 32; ++u) {
        int idx = tid + u * 256;          // over W1[512][16]
        int k = idx >> 4, j = idx & 15;
        int slot = (j >> 2) ^ ((k >> 2) & 3);
        Wl[k * 16 + slot * 4 + (j & 3)] = W1[idx];
    }
    __syncthreads();

    const int sub  = tid & 15;            // k-slice owner within quarter-wave
    const int grp  = tid >> 4;            // 0..15: quarter-wave id in block
    const int rbase = blockIdx.x * 64 + grp * 4;

    const int r0 = min(rbase + 0, N_NODES - 1);
    const int r1 = min(rbase + 1, N_NODES - 1);
    const int r2 = min(rbase + 2, N_NODES - 1);
    const int r3 = min(rbase + 3, N_NODES - 1);
    const float* xp0 = x + (size_t)r0 * N_FEAT + sub * 4;
    const float* xp1 = x + (size_t)r1 * N_FEAT + sub * 4;
    const float* xp2 = x + (size_t)r2 * N_FEAT + sub * 4;
    const float* xp3 = x + (size_t)r3 * N_FEAT + sub * 4;

    float a0[16], a1[16], a2[16], a3[16];
    #pragma unroll
    for (int j = 0; j < 16; ++j) { a0[j] = 0.f; a1[j] = 0.f; a2[j] = 0.f; a3[j] = 0.f; }

    const int sw = sub & 3;               // = (k>>2)&3 for this lane's k's

    #pragma unroll 1
    for (int i = 0; i < 8; ++i) {
        const float4 xa = *(const float4*)(xp0 + i * 64);
        const float4 xb = *(const float4*)(xp1 + i * 64);
        const float4 xc = *(const float4*)(xp2 + i * 64);
        const float4 xd = *(const float4*)(xp3 + i * 64);
        const int kb = i * 64 + sub * 4;
        #pragma unroll
        for (int t = 0; t < 4; ++t) {
            const float* wr = &Wl[(kb + t) * 16];
            const float4 w0 = *(const float4*)(wr + ((0 ^ sw) << 2));
            const float4 w1 = *(const float4*)(wr + ((1 ^ sw) << 2));
            const float4 w2 = *(const float4*)(wr + ((2 ^ sw) << 2));
            const float4 w3 = *(const float4*)(wr + ((3 ^ sw) << 2));
            const float fa = (t == 0) ? xa.x : (t == 1) ? xa.y : (t == 2) ? xa.z : xa.w;
            const float fb = (t == 0) ? xb.x : (t == 1) ? xb.y : (t == 2) ? xb.z : xb.w;
            const float fc = (t == 0) ? xc.x : (t == 1) ? xc.y : (t == 2) ? xc.z : xc.w;
            const float fd = (t == 0) ? xd.x : (t == 1) ? xd.y : (t == 2) ? xd.z : xd.w;
            FMA16(a0, fa, w0, w1, w2, w3)
            FMA16(a1, fb, w0, w1, w2, w3)
            FMA16(a2, fc, w0, w1, w2, w3)
            FMA16(a3, fd, w0, w1, w2, w3)
        }
    }

    // butterfly reduce over the 16-lane group (xor bits 0..3 of lane)
    #pragma unroll
    for (int m = 1; m <= 8; m <<= 1) {
        #pragma unroll
        for (int j = 0; j < 16; ++j) {
            a0[j] += __shfl_xor(a0[j], m, 64);
            a1[j] += __shfl_xor(a1[j], m, 64);
            a2[j] += __shfl_xor(a2[j], m, 64);
            a3[j] += __shfl_xor(a3[j], m, 64);
        }
    }

    // lane `sub` writes column j = sub of its 4 rows (static-index select)
    float v0 = a0[0], v1 = a1[0], v2 = a2[0], v3 = a3[0];
    #pragma unroll
    for (int j = 1; j < 16; ++j) {
        const bool p = (sub == j);
        v0 = p ? a0[j] : v0;
        v1 = p ? a1[j] : v1;
        v2 = p ? a2[j] : v2;
        v3 = p ? a3[j] : v3;
    }
    if (rbase + 0 < N_NODES) out[(rbase + 0) * N_HID + sub] = v0;
    if (rbase + 1 < N_NODES) out[(rbase + 1) * N_HID + sub] = v1;
    if (rbase + 2 < N_NODES) out[(rbase + 2) * N_HID + sub] = v2;
    if (rbase + 3 < N_NODES) out[(rbase + 3) * N_HID + sub] = v3;
}

// ---------------- tier-2 fallback: one-shot random scatter ----------------
__global__ __launch_bounds__(256) void k_scatter(const int* __restrict__ src,
                                                 const int* __restrict__ dst,
                                                 const float* __restrict__ ew,
                                                 const int* __restrict__ part,
                                                 const int* __restrict__ boffs,
                                                 int* __restrict__ cur,
                                                 int2* __restrict__ srt) {
    int e = blockIdx.x * 256 + threadIdx.x;
    if (e >= N_EDGES) return;
    int d = dst[e];
    int pos = part[d] + boffs[d >> 12] + atomicAdd(&cur[d], 1);
    srt[pos] = make_int2(src[e], __float_as_int(ew[e]));
}

// ---------------- tier-3 fallback kernels (atomic scatter) ----------------
__global__ __launch_bounds__(256) void k_edge(const int* __restrict__ src,
                                              const int* __restrict__ dst,
                                              const float* __restrict__ ew,
                                              const float* __restrict__ tab,
                                              float* __restrict__ out) {
    int gid = blockIdx.x * 256 + threadIdx.x;
    int e = gid >> 2;
    if (e >= N_EDGES) return;
    int j4 = (gid & 3) << 2;
    int s = src[e];
    int d = dst[e];
    float w = ew[e];
    const float4 v = *(const float4*)&tab[s * N_HID + j4];
    float* o = &out[d * N_HID + j4];
    atomicAdd(o + 0, v.x * w);
    atomicAdd(o + 1, v.y * w);
    atomicAdd(o + 2, v.z * w);
    atomicAdd(o + 3, v.w * w);
}

__global__ void k_relu_bias(float* __restrict__ h, const float* __restrict__ b1) {
    int i = blockIdx.x * 256 + threadIdx.x;
    if (i >= N_NODES * 4) return;
    float4 v = ((float4*)h)[i];
    int jb = (i & 3) << 2;
    v.x = fmaxf(v.x + b1[jb + 0], 0.f);
    v.y = fmaxf(v.y + b1[jb + 1], 0.f);
    v.z = fmaxf(v.z + b1[jb + 2], 0.f);
    v.w = fmaxf(v.w + b1[jb + 3], 0.f);
    ((float4*)h)[i] = v;
}

// ---------------- out = log_softmax(agg2 @ W2 + b2) ----------------
__global__ __launch_bounds__(256) void k_out(const float* __restrict__ agg2,
                                             const float* __restrict__ W2,
                                             const float* __restrict__ b2,
                                             float* __restrict__ out) {
    int row  = (blockIdx.x * 256 + threadIdx.x) >> 6;
    int lane = threadIdx.x & 63;
    if (row >= N_NODES) return;

    const float* a = &agg2[row * N_HID];
    float av[16];
    #pragma unroll
    for (int k = 0; k < 16; k += 4) {
        float4 t = *(const float4*)&a[k];
        av[k + 0] = t.x; av[k + 1] = t.y; av[k + 2] = t.z; av[k + 3] = t.w;
    }

    int c = (lane < N_CLS) ? lane : 0;
    float acc = b2[c];
    #pragma unroll
    for (int k = 0; k < 16; ++k)
        acc = fmaf(av[k], W2[k * N_CLS + c], acc);

    float mval = (lane < N_CLS) ? acc : -INFINITY;
    #pragma unroll
    for (int m = 32; m; m >>= 1) mval = fmaxf(mval, __shfl_xor(mval, m, 64));
    float ex = (lane < N_CLS) ? expf(acc - mval) : 0.f;
    float s = ex;
    #pragma unroll
    for (int m = 32; m; m >>= 1) s += __shfl_xor(s, m, 64);
    float ls = logf(s);
    if (lane < N_CLS) out[row * N_CLS + lane] = acc - mval - ls;
}

extern "C" void kernel_launch(void* const* d_in, const int* in_sizes, int n_in,
                              void* d_out, int out_size, void* d_ws, size_t ws_size,
                              hipStream_t stream) {
    const float* x    = (const float*)d_in[0];
    const int*   esrc = (const int*)  d_in[1];
    const int*   edst = (const int*)  d_in[2];
    const float* ew   = (const float*)d_in[3];
    const float* W1   = (const float*)d_in[4];
    const float* b1   = (const float*)d_in[5];
    const float* W2   = (const float*)d_in[6];
    const float* b2   = (const float*)d_in[7];
    float* out = (float*)d_out;

    // ---- tier-1 (binned) workspace layout, 4-byte units ----
    // bin  : 6.4M ints (25.6 MB) — dead after k_place; buf0/buf1 alias here
    // srt  : 6.4M ints (25.6 MB)
    // cnt  : CNT_PAD; curb : NB_PAD (zeroed together -> adjacent)
    // part : CNT_PAD; bsum/boffs : 64 each; offb : NB_PAD
    // (cur is tier-2-only and NOT part of tier-1's requirement)
    int* ws = (int*)d_ws;
    int2*  bin  = (int2*)ws;
    float* buf0 = (float*)ws;                              // alias of bin
    float* buf1 = buf0 + (size_t)N_NODES * N_HID;          // alias of bin (+6.4MB)
    int2*  srt  = (int2*)(ws + 2 * (size_t)N_EDGES);
    int*   cnt  = ws + 4 * (size_t)N_EDGES;
    int*   curb = cnt + CNT_PAD;
    int*   part = curb + NB_PAD;
    int*   bsum = part + CNT_PAD;
    int*   boffs = bsum + 64;
    int*   offb  = boffs + 64;
    const size_t need1 = ((size_t)(offb + NB_PAD) - (size_t)d_ws);

    const int n4 = N_NODES * 4;
    const int zgrid = (n4 + 255) / 256;
    const int egrid = (N_EDGES + 255) / 256;

    if (ws_size >= need1) {
        // ---- tier 1: binned CSR build ----
        k_zero_i<<<(CNT_PAD + NB_PAD + 255) / 256, 256, 0, stream>>>(cnt, CNT_PAD + NB_PAD);
        k_hist<<<egrid, 256, 0, stream>>>(edst, cnt);
        k_scan1<<<N_SCAN_BLKS, 256, 0, stream>>>(cnt, part, bsum);
        k_scan2<<<1, 64, 0, stream>>>(bsum, boffs, part, offb);
        k_bin<<<(N_EDGES + BIN_CHUNK - 1) / BIN_CHUNK, 256, 0, stream>>>(
            esrc, edst, ew, offb, curb, bin);
        k_place<<<NB, 256, 0, stream>>>(part, boffs, offb, bin, srt);
        // bin region is now dead -> buf0/buf1 reuse it
        k_gemm1<<<(N_NODES + 63) / 64, 256, 0, stream>>>(x, W1, buf0);
        k_agg<1><<<(N_NODES * 16 + 255) / 256, 256, 0, stream>>>(
            part, boffs, cnt, srt, buf0, b1, buf1);
        k_agg<0><<<(N_NODES * 16 + 255) / 256, 256, 0, stream>>>(
            part, boffs, cnt, srt, buf1, b1 /*unused*/, buf0);
        k_out<<<(N_NODES + 3) / 4, 256, 0, stream>>>(buf0, W2, b2, out);
        return;
    }

    // ---- tier 2: old CSR path (random scatter), needs ~39.7 MB ----
    {
        int2*  srt2  = (int2*)ws;
        float* f0 = (float*)(ws + 2 * (size_t)N_EDGES);
        float* f1 = f0 + (size_t)N_NODES * N_HID;
        int*   cnt2 = (int*)(f1 + (size_t)N_NODES * N_HID);
        int*   cur2 = cnt2 + CNT_PAD;
        int*   part2 = cur2 + CNT_PAD;
        int*   bsum2 = part2 + CNT_PAD;
        int*   boffs2 = bsum2 + 64;
        int*   offb2  = boffs2 + 64;
        const size_t need2 = ((size_t)(offb2 + NB_PAD) - (size_t)d_ws);
        if (ws_size >= need2) {
            k_zero_i<<<(2 * CNT_PAD + 255) / 256, 256, 0, stream>>>(cnt2, 2 * CNT_PAD);
            k_hist<<<egrid, 256, 0, stream>>>(edst, cnt2);
            k_scan1<<<N_SCAN_BLKS, 256, 0, stream>>>(cnt2, part2, bsum2);
            k_scan2<<<1, 64, 0, stream>>>(bsum2, boffs2, part2, offb2);
            k_scatter<<<egrid, 256, 0, stream>>>(esrc, edst, ew, part2, boffs2, cur2, srt2);
            k_gemm1<<<(N_NODES + 63) / 64, 256, 0, stream>>>(x, W1, f0);
            k_agg<1><<<(N_NODES * 16 + 255) / 256, 256, 0, stream>>>(
                part2, boffs2, cnt2, srt2, f0, b1, f1);
            k_agg<0><<<(N_NODES * 16 + 255) / 256, 256, 0, stream>>>(
                part2, boffs2, cnt2, srt2, f1, b1 /*unused*/, f0);
            k_out<<<(N_NODES + 3) / 4, 256, 0, stream>>>(f0, W2, b2, out);
            return;
        }
    }

    // ---- tier 3: atomic path ----
    {
        float* fb0 = (float*)d_ws;
        float* fb1 = fb0 + (size_t)N_NODES * N_HID;
        k_zero<<<zgrid, 256, 0, stream>>>((float4*)fb1, n4);
        k_gemm1<<<(N_NODES + 63) / 64, 256, 0, stream>>>(x, W1, fb0);
        k_edge<<<(N_EDGES * 4 + 255) / 256, 256, 0, stream>>>(esrc, edst, ew, fb0, fb1);
        k_relu_bias<<<zgrid, 256, 0, stream>>>(fb1, b1);
        k_zero<<<zgrid, 256, 0, stream>>>((float4*)fb0, n4);
        k_edge<<<(N_EDGES * 4 + 255) / 256, 256, 0, stream>>>(esrc, edst, ew, fb1, fb0);
        k_out<<<(N_NODES + 3) / 4, 256, 0, stream>>>(fb0, W2, b2, out);
    }
}

// Round 8
// 568.740 us; speedup vs baseline: 3.2452x; 1.2215x over previous
//
#include <hip/hip_runtime.h>
#include <math.h>

#define N_NODES 100000
#define N_EDGES 3200000
#define N_FEAT  512
#define N_HID   16
#define N_CLS   40

#define CNT_PAD 100352          // N_NODES rounded up (alignment slack)
#define SCAN_BLK 4096           // elements scanned per block (256 thr * 16)
#define N_SCAN_BLKS 25          // ceil(100000/4096)

#define BUCKET_SHIFT 9          // 512 nodes per bucket
#define NB 196                  // ceil(100000/512)
#define NB_PAD 256
#define BIN_CHUNK 4096          // edges per k_bin block (16 per thread)
#define CAP 17408               // slots per bucket region (mean 16384, +8 sigma)

// ---------------- zero fill (float4) ----------------
__global__ void k_zero(float4* __restrict__ p, int n4) {
    int i = blockIdx.x * 256 + threadIdx.x;
    if (i < n4) p[i] = make_float4(0.f, 0.f, 0.f, 0.f);
}

// ---------------- zero fill (ints) ----------------
__global__ void k_zero_i(int* __restrict__ p, int n) {
    int i = blockIdx.x * 256 + threadIdx.x;
    if (i < n) p[i] = 0;
}

// ---------------- pass A: bin edges into fixed-CAP bucket regions ----------
// Per block: LDS bucket histogram -> one global ticket per touched bucket ->
// clustered writes. Record packs (src | dstlo<<17, w_bits): src<2^17, dstlo<2^9.
// curb[b] ends up = total records in bucket b.
__global__ __launch_bounds__(256) void k_bin(const int* __restrict__ src,
                                             const int* __restrict__ dst,
                                             const float* __restrict__ ew,
                                             int* __restrict__ curb,
                                             int2* __restrict__ bin) {
    __shared__ int lcnt[NB];
    __shared__ int lbase[NB];
    const int tid = threadIdx.x;
    const int e0 = blockIdx.x * BIN_CHUNK;
    if (tid < NB) lcnt[tid] = 0;
    __syncthreads();
    // phase 1: local bucket histogram
    #pragma unroll
    for (int u = 0; u < 16; ++u) {
        int e = e0 + u * 256 + tid;
        if (e < N_EDGES) atomicAdd(&lcnt[dst[e] >> BUCKET_SHIFT], 1);
    }
    __syncthreads();
    // phase 2: reserve a contiguous run in the bucket's fixed region
    if (tid < NB) {
        int c = lcnt[tid];
        lbase[tid] = (c > 0) ? (tid * CAP + atomicAdd(&curb[tid], c)) : 0;
        lcnt[tid] = 0;
    }
    __syncthreads();
    // phase 3: write records into the reserved runs
    #pragma unroll
    for (int u = 0; u < 16; ++u) {
        int e = e0 + u * 256 + tid;
        if (e < N_EDGES) {
            int d = dst[e];
            int b = d >> BUCKET_SHIFT;
            int rank = atomicAdd(&lcnt[b], 1);
            bin[lbase[b] + rank] =
                make_int2(src[e] | ((d & 511) << 17), __float_as_int(ew[e]));
        }
    }
}

// ---------------- scan of bucket totals -> global CSR base per bucket ----------
__global__ void k_bscan(const int* __restrict__ curb, int* __restrict__ bbase) {
    if (threadIdx.x == 0) {
        int run = 0;
        for (int b = 0; b < NB; ++b) { bbase[b] = run; run += curb[b]; }
    }
}

// ---------------- pass B: per-bucket count + scan + compact into srt ----------
// One block per bucket. Produces start[]/cnt[] (replaces global hist+scan) and
// srt (node-sorted compact CSR). Bucket srt window ~136 KB: L2-resident.
__global__ __launch_bounds__(256) void k_place2(const int* __restrict__ curb,
                                                const int* __restrict__ bbase,
                                                const int2* __restrict__ bin,
                                                int2* __restrict__ srt,
                                                int* __restrict__ start,
                                                int* __restrict__ cnt) {
    __shared__ int lcnt[512];
    __shared__ int lpre[512];
    __shared__ int lcur[512];
    __shared__ int ssum[256];
    const int b = blockIdx.x;
    const int tid = threadIdx.x;
    lcnt[tid] = 0; lcnt[tid + 256] = 0;
    lcur[tid] = 0; lcur[tid + 256] = 0;
    __syncthreads();
    const int c = curb[b];
    const int2* bp = bin + (size_t)b * CAP;
    // per-node counts within the bucket
    for (int i = tid; i < c; i += 256)
        atomicAdd(&lcnt[(bp[i].x >> 17) & 511], 1);
    __syncthreads();
    // exclusive scan of lcnt[512]: pair-sum -> 256-wide Hillis-Steele -> expand
    const int p0 = lcnt[2 * tid], p1 = lcnt[2 * tid + 1];
    ssum[tid] = p0 + p1;
    __syncthreads();
    for (int off = 1; off < 256; off <<= 1) {
        int t = (tid >= off) ? ssum[tid - off] : 0;
        __syncthreads();
        ssum[tid] += t;
        __syncthreads();
    }
    const int ex = (tid > 0) ? ssum[tid - 1] : 0;
    lpre[2 * tid] = ex;
    lpre[2 * tid + 1] = ex + p0;
    __syncthreads();
    // emit start/cnt (coalesced)
    const int node0 = b << BUCKET_SHIFT;
    const int gb = bbase[b];
    for (int i = tid; i < 512; i += 256) {
        int node = node0 + i;
        if (node < N_NODES) { start[node] = gb + lpre[i]; cnt[node] = lcnt[i]; }
    }
    // scatter records to node-sorted positions
    for (int i = tid; i < c; i += 256) {
        int2 rec = bp[i];
        int dlo = (rec.x >> 17) & 511;
        int rank = atomicAdd(&lcur[dlo], 1);
        srt[gb + lpre[dlo] + rank] = make_int2(rec.x & 0x1FFFF, rec.y);
    }
}

// ---------------- CSR aggregation: out[n,j] = sum_{e: dst=n} w_e * tab[src_e, j] ----
// 16 lanes per node (lane = feature). 4-way unrolled edge loop for gather ILP.
// RELU=1 fuses out = relu(agg + bias).
template <int RELU>
__global__ __launch_bounds__(256) void k_agg(const int* __restrict__ start,
                                             const int* __restrict__ cnt,
                                             const int2* __restrict__ srt,
                                             const float* __restrict__ tab,
                                             const float* __restrict__ bias,
                                             float* __restrict__ out) {
    int gid = blockIdx.x * 256 + threadIdx.x;
    int node = gid >> 4;
    int j = gid & 15;
    if (node >= N_NODES) return;
    int s0 = start[node];
    int len = cnt[node];
    float a0 = 0.f, a1 = 0.f, a2 = 0.f, a3 = 0.f;
    int k = 0;
    for (; k + 4 <= len; k += 4) {
        int2 e0 = srt[s0 + k + 0];
        int2 e1 = srt[s0 + k + 1];
        int2 e2 = srt[s0 + k + 2];
        int2 e3 = srt[s0 + k + 3];
        a0 += __int_as_float(e0.y) * tab[e0.x * N_HID + j];
        a1 += __int_as_float(e1.y) * tab[e1.x * N_HID + j];
        a2 += __int_as_float(e2.y) * tab[e2.x * N_HID + j];
        a3 += __int_as_float(e3.y) * tab[e3.x * N_HID + j];
    }
    for (; k < len; ++k) {
        int2 e = srt[s0 + k];
        a0 += __int_as_float(e.y) * tab[e.x * N_HID + j];
    }
    float v = (a0 + a2) + (a1 + a3);
    if (RELU) v = fmaxf(v + bias[j], 0.f);
    out[node * N_HID + j] = v;
}

// ---------------- GEMM1: support1[N,16] = X[N,512] @ W1[512,16] ----------------
// quarter-wave (16 lanes) per 4 rows, k split across the 16 lanes.
// #pragma unroll 1 on the K-chunk loop prevents the load-hoist VGPR blowup.
#define FMA16(A, F, W0, W1v, W2v, W3v)                                   \
    A[0] += F * W0.x;  A[1] += F * W0.y;  A[2]  += F * W0.z;  A[3]  += F * W0.w;  \
    A[4] += F * W1v.x; A[5] += F * W1v.y; A[6]  += F * W1v.z; A[7]  += F * W1v.w; \
    A[8] += F * W2v.x; A[9] += F * W2v.y; A[10] += F * W2v.z; A[11] += F * W2v.w; \
    A[12]+= F * W3v.x; A[13]+= F * W3v.y; A[14] += F * W3v.z; A[15] += F * W3v.w;

__global__ __launch_bounds__(256) void k_gemm1(const float* __restrict__ x,
                                               const float* __restrict__ W1,
                                               float* __restrict__ out) {
    __shared__ float Wl[512 * 16];
    const int tid = threadIdx.x;
    #pragma unroll
    for (int u = 0; u < 32; ++u) {
        int idx = tid + u * 256;          // over W1[512][16]
        int k = idx >> 4, j = idx & 15;
        int slot = (j >> 2) ^ ((k >> 2) & 3);
        Wl[k * 16 + slot * 4 + (j & 3)] = W1[idx];
    }
    __syncthreads();

    const int sub  = tid & 15;            // k-slice owner within quarter-wave
    const int grp  = tid >> 4;            // 0..15: quarter-wave id in block
    const int rbase = blockIdx.x * 64 + grp * 4;

    const int r0 = min(rbase + 0, N_NODES - 1);
    const int r1 = min(rbase + 1, N_NODES - 1);
    const int r2 = min(rbase + 2, N_NODES - 1);
    const int r3 = min(rbase + 3, N_NODES - 1);
    const float* xp0 = x + (size_t)r0 * N_FEAT + sub * 4;
    const float* xp1 = x + (size_t)r1 * N_FEAT + sub * 4;
    const float* xp2 = x + (size_t)r2 * N_FEAT + sub * 4;
    const float* xp3 = x + (size_t)r3 * N_FEAT + sub * 4;

    float a0[16], a1[16], a2[16], a3[16];
    #pragma unroll
    for (int j = 0; j < 16; ++j) { a0[j] = 0.f; a1[j] = 0.f; a2[j] = 0.f; a3[j] = 0.f; }

    const int sw = sub & 3;               // = (k>>2)&3 for this lane's k's

    #pragma unroll 1
    for (int i = 0; i < 8; ++i) {
        const float4 xa = *(const float4*)(xp0 + i * 64);
        const float4 xb = *(const float4*)(xp1 + i * 64);
        const float4 xc = *(const float4*)(xp2 + i * 64);
        const float4 xd = *(const float4*)(xp3 + i * 64);
        const int kb = i * 64 + sub * 4;
        #pragma unroll
        for (int t = 0; t < 4; ++t) {
            const float* wr = &Wl[(kb + t) * 16];
            const float4 w0 = *(const float4*)(wr + ((0 ^ sw) << 2));
            const float4 w1 = *(const float4*)(wr + ((1 ^ sw) << 2));
            const float4 w2 = *(const float4*)(wr + ((2 ^ sw) << 2));
            const float4 w3 = *(const float4*)(wr + ((3 ^ sw) << 2));
            const float fa = (t == 0) ? xa.x : (t == 1) ? xa.y : (t == 2) ? xa.z : xa.w;
            const float fb = (t == 0) ? xb.x : (t == 1) ? xb.y : (t == 2) ? xb.z : xb.w;
            const float fc = (t == 0) ? xc.x : (t == 1) ? xc.y : (t == 2) ? xc.z : xc.w;
            const float fd = (t == 0) ? xd.x : (t == 1) ? xd.y : (t == 2) ? xd.z : xd.w;
            FMA16(a0, fa, w0, w1, w2, w3)
            FMA16(a1, fb, w0, w1, w2, w3)
            FMA16(a2, fc, w0, w1, w2, w3)
            FMA16(a3, fd, w0, w1, w2, w3)
        }
    }

    // butterfly reduce over the 16-lane group (xor bits 0..3 of lane)
    #pragma unroll
    for (int m = 1; m <= 8; m <<= 1) {
        #pragma unroll
        for (int j = 0; j < 16; ++j) {
            a0[j] += __shfl_xor(a0[j], m, 64);
            a1[j] += __shfl_xor(a1[j], m, 64);
            a2[j] += __shfl_xor(a2[j], m, 64);
            a3[j] += __shfl_xor(a3[j], m, 64);
        }
    }

    // lane `sub` writes column j = sub of its 4 rows (static-index select)
    float v0 = a0[0], v1 = a1[0], v2 = a2[0], v3 = a3[0];
    #pragma unroll
    for (int j = 1; j < 16; ++j) {
        const bool p = (sub == j);
        v0 = p ? a0[j] : v0;
        v1 = p ? a1[j] : v1;
        v2 = p ? a2[j] : v2;
        v3 = p ? a3[j] : v3;
    }
    if (rbase + 0 < N_NODES) out[(rbase + 0) * N_HID + sub] = v0;
    if (rbase + 1 < N_NODES) out[(rbase + 1) * N_HID + sub] = v1;
    if (rbase + 2 < N_NODES) out[(rbase + 2) * N_HID + sub] = v2;
    if (rbase + 3 < N_NODES) out[(rbase + 3) * N_HID + sub] = v3;
}

// ======== tier-2 fallback machinery (global hist + scan + random scatter) ========
__global__ __launch_bounds__(256) void k_hist(const int* __restrict__ dst,
                                              int* __restrict__ cnt) {
    int e = blockIdx.x * 256 + threadIdx.x;
    if (e < N_EDGES) atomicAdd(&cnt[dst[e]], 1);
}

__global__ __launch_bounds__(256) void k_scan1(const int* __restrict__ cnt,
                                               int* __restrict__ part,
                                               int* __restrict__ bsum) {
    __shared__ int sh[256];
    const int tid = threadIdx.x;
    const int base = blockIdx.x * SCAN_BLK + tid * 16;
    int v[16];
    int s = 0;
    #pragma unroll
    for (int i = 0; i < 16; ++i) {
        v[i] = (base + i < N_NODES) ? cnt[base + i] : 0;
        s += v[i];
    }
    sh[tid] = s;
    __syncthreads();
    for (int off = 1; off < 256; off <<= 1) {
        int t = (tid >= off) ? sh[tid - off] : 0;
        __syncthreads();
        sh[tid] += t;
        __syncthreads();
    }
    int ex = (tid > 0) ? sh[tid - 1] : 0;
    if (tid == 255) bsum[blockIdx.x] = sh[255];
    int run = ex;
    #pragma unroll
    for (int i = 0; i < 16; ++i) {
        if (base + i < N_NODES) part[base + i] = run;
        run += v[i];
    }
}

// combine: start[node] = part[node] + boffs[node>>12] (after a serial boffs scan)
__global__ void k_scan2(const int* __restrict__ bsum, int* __restrict__ boffs) {
    if (threadIdx.x == 0) {
        int run = 0;
        for (int i = 0; i < N_SCAN_BLKS; ++i) { boffs[i] = run; run += bsum[i]; }
    }
}

__global__ __launch_bounds__(256) void k_mkstart(const int* __restrict__ part,
                                                 const int* __restrict__ boffs,
                                                 int* __restrict__ start) {
    int n = blockIdx.x * 256 + threadIdx.x;
    if (n < N_NODES) start[n] = part[n] + boffs[n >> 12];
}

__global__ __launch_bounds__(256) void k_scatter(const int* __restrict__ src,
                                                 const int* __restrict__ dst,
                                                 const float* __restrict__ ew,
                                                 const int* __restrict__ start,
                                                 int* __restrict__ cur,
                                                 int2* __restrict__ srt) {
    int e = blockIdx.x * 256 + threadIdx.x;
    if (e >= N_EDGES) return;
    int d = dst[e];
    int pos = start[d] + atomicAdd(&cur[d], 1);
    srt[pos] = make_int2(src[e], __float_as_int(ew[e]));
}

// ======== tier-3 fallback (direct atomic scatter) ========
__global__ __launch_bounds__(256) void k_edge(const int* __restrict__ src,
                                              const int* __restrict__ dst,
                                              const float* __restrict__ ew,
                                              const float* __restrict__ tab,
                                              float* __restrict__ out) {
    int gid = blockIdx.x * 256 + threadIdx.x;
    int e = gid >> 2;
    if (e >= N_EDGES) return;
    int j4 = (gid & 3) << 2;
    int s = src[e];
    int d = dst[e];
    float w = ew[e];
    const float4 v = *(const float4*)&tab[s * N_HID + j4];
    float* o = &out[d * N_HID + j4];
    atomicAdd(o + 0, v.x * w);
    atomicAdd(o + 1, v.y * w);
    atomicAdd(o + 2, v.z * w);
    atomicAdd(o + 3, v.w * w);
}

__global__ void k_relu_bias(float* __restrict__ h, const float* __restrict__ b1) {
    int i = blockIdx.x * 256 + threadIdx.x;
    if (i >= N_NODES * 4) return;
    float4 v = ((float4*)h)[i];
    int jb = (i & 3) << 2;
    v.x = fmaxf(v.x + b1[jb + 0], 0.f);
    v.y = fmaxf(v.y + b1[jb + 1], 0.f);
    v.z = fmaxf(v.z + b1[jb + 2], 0.f);
    v.w = fmaxf(v.w + b1[jb + 3], 0.f);
    ((float4*)h)[i] = v;
}

// ---------------- out = log_softmax(agg2 @ W2 + b2) ----------------
__global__ __launch_bounds__(256) void k_out(const float* __restrict__ agg2,
                                             const float* __restrict__ W2,
                                             const float* __restrict__ b2,
                                             float* __restrict__ out) {
    int row  = (blockIdx.x * 256 + threadIdx.x) >> 6;
    int lane = threadIdx.x & 63;
    if (row >= N_NODES) return;

    const float* a = &agg2[row * N_HID];
    float av[16];
    #pragma unroll
    for (int k = 0; k < 16; k += 4) {
        float4 t = *(const float4*)&a[k];
        av[k + 0] = t.x; av[k + 1] = t.y; av[k + 2] = t.z; av[k + 3] = t.w;
    }

    int c = (lane < N_CLS) ? lane : 0;
    float acc = b2[c];
    #pragma unroll
    for (int k = 0; k < 16; ++k)
        acc = fmaf(av[k], W2[k * N_CLS + c], acc);

    float mval = (lane < N_CLS) ? acc : -INFINITY;
    #pragma unroll
    for (int m = 32; m; m >>= 1) mval = fmaxf(mval, __shfl_xor(mval, m, 64));
    float ex = (lane < N_CLS) ? expf(acc - mval) : 0.f;
    float s = ex;
    #pragma unroll
    for (int m = 32; m; m >>= 1) s += __shfl_xor(s, m, 64);
    float ls = logf(s);
    if (lane < N_CLS) out[row * N_CLS + lane] = acc - mval - ls;
}

extern "C" void kernel_launch(void* const* d_in, const int* in_sizes, int n_in,
                              void* d_out, int out_size, void* d_ws, size_t ws_size,
                              hipStream_t stream) {
    const float* x    = (const float*)d_in[0];
    const int*   esrc = (const int*)  d_in[1];
    const int*   edst = (const int*)  d_in[2];
    const float* ew   = (const float*)d_in[3];
    const float* W1   = (const float*)d_in[4];
    const float* b1   = (const float*)d_in[5];
    const float* W2   = (const float*)d_in[6];
    const float* b2   = (const float*)d_in[7];
    float* out = (float*)d_out;

    // ---- tier-1 workspace layout, 4-byte units ----
    // bin  : NB*CAP int2 = 6,823,936 ints (27.3 MB) — dead after k_place2;
    //        buf0/buf1 (3.2M ints) alias here
    // srt  : 6.4M ints (25.6 MB)
    // start: CNT_PAD; cnt: CNT_PAD; curb: NB_PAD; bbase: NB_PAD
    int* ws = (int*)d_ws;
    int2*  bin  = (int2*)ws;
    float* buf0 = (float*)ws;                              // alias of bin
    float* buf1 = buf0 + (size_t)N_NODES * N_HID;          // alias of bin (+6.4MB)
    int2*  srt  = (int2*)(ws + 2 * (size_t)NB * CAP);
    int*   start = ws + 2 * (size_t)NB * CAP + 2 * (size_t)N_EDGES;
    int*   cnt   = start + CNT_PAD;
    int*   curb  = cnt + CNT_PAD;
    int*   bbase = curb + NB_PAD;
    const size_t need1 = ((size_t)(bbase + NB_PAD) - (size_t)d_ws);

    const int n4 = N_NODES * 4;
    const int zgrid = (n4 + 255) / 256;
    const int egrid = (N_EDGES + 255) / 256;

    if (ws_size >= need1) {
        // ---- tier 1: bucket-local CSR build (no global hist/scan) ----
        k_zero_i<<<1, 256, 0, stream>>>(curb, NB_PAD);
        k_bin<<<(N_EDGES + BIN_CHUNK - 1) / BIN_CHUNK, 256, 0, stream>>>(
            esrc, edst, ew, curb, bin);
        k_bscan<<<1, 64, 0, stream>>>(curb, bbase);
        k_place2<<<NB, 256, 0, stream>>>(curb, bbase, bin, srt, start, cnt);
        // bin region is now dead -> buf0/buf1 reuse it
        k_gemm1<<<(N_NODES + 63) / 64, 256, 0, stream>>>(x, W1, buf0);
        k_agg<1><<<(N_NODES * 16 + 255) / 256, 256, 0, stream>>>(
            start, cnt, srt, buf0, b1, buf1);
        k_agg<0><<<(N_NODES * 16 + 255) / 256, 256, 0, stream>>>(
            start, cnt, srt, buf1, b1 /*unused*/, buf0);
        k_out<<<(N_NODES + 3) / 4, 256, 0, stream>>>(buf0, W2, b2, out);
        return;
    }

    // ---- tier 2: global hist + scan + random scatter CSR (~40 MB) ----
    {
        int2*  srt2  = (int2*)ws;
        float* f0 = (float*)(ws + 2 * (size_t)N_EDGES);
        float* f1 = f0 + (size_t)N_NODES * N_HID;
        int*   cnt2 = (int*)(f1 + (size_t)N_NODES * N_HID);
        int*   cur2 = cnt2 + CNT_PAD;
        int*   part2 = cur2 + CNT_PAD;
        int*   start2 = part2 + CNT_PAD;
        int*   bsum2 = start2 + CNT_PAD;
        int*   boffs2 = bsum2 + 64;
        const size_t need2 = ((size_t)(boffs2 + 64) - (size_t)d_ws);
        if (ws_size >= need2) {
            k_zero_i<<<(2 * CNT_PAD + 255) / 256, 256, 0, stream>>>(cnt2, 2 * CNT_PAD);
            k_hist<<<egrid, 256, 0, stream>>>(edst, cnt2);
            k_scan1<<<N_SCAN_BLKS, 256, 0, stream>>>(cnt2, part2, bsum2);
            k_scan2<<<1, 64, 0, stream>>>(bsum2, boffs2);
            k_mkstart<<<(N_NODES + 255) / 256, 256, 0, stream>>>(part2, boffs2, start2);
            k_scatter<<<egrid, 256, 0, stream>>>(esrc, edst, ew, start2, cur2, srt2);
            k_gemm1<<<(N_NODES + 63) / 64, 256, 0, stream>>>(x, W1, f0);
            k_agg<1><<<(N_NODES * 16 + 255) / 256, 256, 0, stream>>>(
                start2, cnt2, srt2, f0, b1, f1);
            k_agg<0><<<(N_NODES * 16 + 255) / 256, 256, 0, stream>>>(
                start2, cnt2, srt2, f1, b1 /*unused*/, f0);
            k_out<<<(N_NODES + 3) / 4, 256, 0, stream>>>(f0, W2, b2, out);
            return;
        }
    }

    // ---- tier 3: atomic path ----
    {
        float* fb0 = (float*)d_ws;
        float* fb1 = fb0 + (size_t)N_NODES * N_HID;
        k_zero<<<zgrid, 256, 0, stream>>>((float4*)fb1, n4);
        k_gemm1<<<(N_NODES + 63) / 64, 256, 0, stream>>>(x, W1, fb0);
        k_edge<<<(N_EDGES * 4 + 255) / 256, 256, 0, stream>>>(esrc, edst, ew, fb0, fb1);
        k_relu_bias<<<zgrid, 256, 0, stream>>>(fb1, b1);
        k_zero<<<zgrid, 256, 0, stream>>>((float4*)fb0, n4);
        k_edge<<<(N_EDGES * 4 + 255) / 256, 256, 0, stream>>>(esrc, edst, ew, fb1, fb0);
        k_out<<<(N_NODES + 3) / 4, 256, 0, stream>>>(fb0, W2, b2, out);
    }
}